// Round 13
// baseline (78.013 us; speedup 1.0000x reference)
//
#include <hip/hip_runtime.h>

static constexpr int NSIDE = 48;
static constexpr int NVOX  = NSIDE * NSIDE * NSIDE;   // 110592
static constexpr float SCALE = 0.041875863808787856f; // ONE_OVER_DIFF_TOT * DIFF_Q
static constexpr float ASCL = 2.8853900817779268f;    // 2*log2(e): tanh arg scale
static constexpr int NDIR  = 13;                      // canonical half of the 26 offsets
static constexpr int PAIRS_PER_BLOCK = 128;           // 4 waves x 32 pairs
static constexpr int BLOCKS_PER_DIR  = NVOX / PAIRS_PER_BLOCK;  // 864

typedef _Float16 f16x2 __attribute__((ext_vector_type(2)));
typedef _Float16 f16x8 __attribute__((ext_vector_type(8)));
typedef float    f32x16 __attribute__((ext_vector_type(16)));

union F16Frag { f16x2 h[4]; f16x8 v; };

// __builtin_amdgcn_cvt_pkrtz returns __fp16x2; bit-cast to our f16x2.
__device__ __forceinline__ f16x2 cvt_pkrtz(float a, float b) {
    return __builtin_bit_cast(f16x2, __builtin_amdgcn_cvt_pkrtz(a, b));
}

// Canonical directions (first nonzero component positive).
__device__ __constant__ int g_ox[NDIR] = { 1, 0, 0,  1, 1, 1, 1, 0, 0,  1, 1, 1, 1 };
__device__ __constant__ int g_oy[NDIR] = { 0, 1, 0,  1,-1, 0, 0, 1, 1,  1, 1,-1,-1 };
__device__ __constant__ int g_oz[NDIR] = { 0, 0, 1,  0, 0, 1,-1, 1,-1,  1,-1, 1,-1 };
__device__ __constant__ float g_dinv[NDIR] = {
    1.f, 1.f, 1.f,
    0.70710678118654752f, 0.70710678118654752f, 0.70710678118654752f,
    0.70710678118654752f, 0.70710678118654752f, 0.70710678118654752f,
    0.57735026918962576f, 0.57735026918962576f, 0.57735026918962576f, 0.57735026918962576f };

// Full 26-neighbor tables for the fallback single-pass kernel.
__device__ __constant__ int c_ox[26] = { 1,-1, 0, 0, 0, 0,
                                         1,-1, 1,-1, 1,-1, 1,-1, 0, 0, 0, 0,
                                         1, 1, 1, 1,-1,-1,-1,-1 };
__device__ __constant__ int c_oy[26] = { 0, 0, 1,-1, 0, 0,
                                         1, 1,-1,-1, 0, 0, 0, 0, 1,-1, 1,-1,
                                         1, 1,-1,-1, 1, 1,-1,-1 };
__device__ __constant__ int c_oz[26] = { 0, 0, 0, 0, 1,-1,
                                         0, 0, 0, 0, 1, 1,-1,-1, 1, 1,-1,-1,
                                         1,-1, 1,-1, 1,-1, 1,-1 };
__device__ __constant__ float c_dinv[26] = {
    1.f, 1.f, 1.f, 1.f, 1.f, 1.f,
    0.70710678118654752f, 0.70710678118654752f, 0.70710678118654752f, 0.70710678118654752f,
    0.70710678118654752f, 0.70710678118654752f, 0.70710678118654752f, 0.70710678118654752f,
    0.70710678118654752f, 0.70710678118654752f, 0.70710678118654752f, 0.70710678118654752f,
    0.57735026918962576f, 0.57735026918962576f, 0.57735026918962576f, 0.57735026918962576f,
    0.57735026918962576f, 0.57735026918962576f, 0.57735026918962576f, 0.57735026918962576f };

__device__ __forceinline__ float fast_tanh(float x) {
    // tanh(x) = 1 - 2/(exp2(2*log2e*x)+1); exact saturation at +-inf.
    float e = __builtin_amdgcn_exp2f(x * ASCL);
    float r = __builtin_amdgcn_rcpf(e + 1.0f);
    return fmaf(-2.0f, r, 1.0f);
}

// f32 Pade[5/4] tanh on FOUR values sharing ONE v_rcp_f32:
//   tanh x ~ x(x^4+105x^2+945)/(15x^4+420x^2+945), clamped to [-1,1].
// 1/di = (prod of other dens) * rcp(prod of all). Max |err| ~1.3e-3 on
// |x|<=4.25 (our pre-activation bound); clamp handles the tail overshoot.
// ~41 VALU + 1 trans per 4 tanh: trans issue (16cy/instr, the R12-measured
// bottleneck) drops 4x -> 1x for these activations.
__device__ __forceinline__ void pade4(float x0, float x1, float x2, float x3,
                                      float& t0, float& t1, float& t2, float& t3) {
    const float u0 = x0 * x0, u1 = x1 * x1, u2 = x2 * x2, u3 = x3 * x3;
    const float n0 = fmaf(u0, u0 + 105.0f, 945.0f);
    const float n1 = fmaf(u1, u1 + 105.0f, 945.0f);
    const float n2 = fmaf(u2, u2 + 105.0f, 945.0f);
    const float n3 = fmaf(u3, u3 + 105.0f, 945.0f);
    const float d0 = fmaf(u0, fmaf(u0, 15.0f, 420.0f), 945.0f);
    const float d1 = fmaf(u1, fmaf(u1, 15.0f, 420.0f), 945.0f);
    const float d2 = fmaf(u2, fmaf(u2, 15.0f, 420.0f), 945.0f);
    const float d3 = fmaf(u3, fmaf(u3, 15.0f, 420.0f), 945.0f);
    const float P  = d0 * d1, Q = d2 * d3;
    const float R  = __builtin_amdgcn_rcpf(P * Q);     // 1 trans / 4 tanh
    const float QR = Q * R, PR = P * R;
    t0 = (x0 * n0) * (d1 * QR);
    t1 = (x1 * n1) * (d0 * QR);
    t2 = (x2 * n2) * (d3 * PR);
    t3 = (x3 * n3) * (d2 * PR);
    t0 = fminf(1.0f, fmaxf(-1.0f, t0));
    t1 = fminf(1.0f, fmaxf(-1.0f, t1));
    t2 = fminf(1.0f, fmaxf(-1.0f, t2));
    t3 = fminf(1.0f, fmaxf(-1.0f, t3));
}

// LDS weight layout (floats):
//  W0:[0,64) b0:[64,80) W1:[80,336) b1:[336,352) W2:[352,608) b2:[608,624)
//  W3:[624,880) b3:[880,896) Wout:[896,912) bout:[912]
#define STAGE_WEIGHTS_256()                                                    \
    __shared__ __align__(16) float sw[916];                                    \
    {                                                                          \
        const int t_ = threadIdx.x;                                            \
        if (t_ <  64) sw[      t_] = W0[t_];                                   \
        if (t_ <  16) sw[ 64 + t_] = b0[t_];                                   \
                      sw[ 80 + t_] = W1[t_];                                   \
        if (t_ <  16) sw[336 + t_] = b1[t_];                                   \
                      sw[352 + t_] = W2[t_];                                   \
        if (t_ <  16) sw[608 + t_] = b2[t_];                                   \
                      sw[624 + t_] = W3[t_];                                   \
        if (t_ <  16) sw[880 + t_] = b3[t_];                                   \
        if (t_ <  16) sw[896 + t_] = Wout[t_];                                 \
        if (t_ ==  0) sw[912]     = bout[0];                                   \
        __syncthreads();                                                       \
    }

// sigma(g,p): k-index owned by lane-group g, fragment slot p. Same convention
// builds A (weights), C (biases) and B (inputs); D-chaining reproduces it, so
// any mismatch vs the HW's internal order cancels (verified on HW in R5).
// Consecutive p within each half are consecutive k -> (p,p+1) pairing is safe.
#define SIG(G, P) (((P) < 4) ? 4 * (G) + (P) : 8 + 4 * (G) + ((P) - 4))

// ---------------------------------------------------------------------------
// MFMA flux kernel: R12 chassis (JIT fragment loads, 40 VGPR, <64 cliff) +
// quad-shared-rcp f32 Pade activations. Per pair: trans instrs 130 -> 18
// (each occupies the issue port ~16cy -- the measured R12 bottleneck);
// activation work moves to the 2cy/instr VALU pipe. Final output tanh stays
// exact (exp2-based).
__global__ __launch_bounds__(256)
void flux_mfma_kernel(const float* __restrict__ q,
                      const float* __restrict__ W0, const float* __restrict__ b0,
                      const float* __restrict__ W1, const float* __restrict__ b1,
                      const float* __restrict__ W2, const float* __restrict__ b2,
                      const float* __restrict__ W3, const float* __restrict__ b3,
                      const float* __restrict__ Wout, const float* __restrict__ bout,
                      float* __restrict__ ws)
{
    STAGE_WEIGHTS_256()

    const int k    = blockIdx.x / BLOCKS_PER_DIR;                // 0..12
    const int rem  = blockIdx.x - k * BLOCKS_PER_DIR;
    const int lane = threadIdx.x & 63;
    const int wv   = threadIdx.x >> 6;
    const int g    = lane >> 5;                                  // feature-half 0/1
    const int vox  = rem * PAIRS_PER_BLOCK + wv * 32 + (lane & 31);

    const int z = vox % NSIDE;
    const int y = (vox / NSIDE) % NSIDE;
    const int x = vox / (NSIDE * NSIDE);
    const int ox = g_ox[k], oy = g_oy[k], oz = g_oz[k];
    const int nx = (ox > 0) ? ((x == NSIDE - 1) ? 0 : x + 1) : x;   // ox in {0,1}
    const int ny = (oy > 0) ? ((y == NSIDE - 1) ? 0 : y + 1)
                            : ((oy < 0) ? ((y == 0) ? NSIDE - 1 : y - 1) : y);
    const int nz = (oz > 0) ? ((z == NSIDE - 1) ? 0 : z + 1)
                            : ((oz < 0) ? ((z == 0) ? NSIDE - 1 : z - 1) : z);

    const float2 own = reinterpret_cast<const float2*>(q)[vox];
    const float2 nbq = reinterpret_cast<const float2*>(q)[(nx * NSIDE + ny) * NSIDE + nz];
    const float o0 = own.x, o1 = own.y;
    const float n0 = nbq.x, n1 = nbq.y;

    const int row = lane & 31;        // A rows >=16 feed only D regs p>=8 (never read)
    const int wr  = (row & 15) * 16;

    // --- layer 0 (4 -> 16): dot4, quad-Pade act, pkrtz-packed ---
    F16Frag ba, bb;
    #pragma unroll
    for (int p = 0; p < 8; p += 2) {
        const int f0 = SIG(g, p), f1 = SIG(g, p + 1);
        const float4 w0v = *reinterpret_cast<const float4*>(&sw[f0 * 4]);
        const float4 w1v = *reinterpret_cast<const float4*>(&sw[f1 * 4]);
        const float bb0 = sw[64 + f0], bb1 = sw[64 + f1];
        float pa0 = fmaf(w0v.x, o0, fmaf(w0v.y, o1, fmaf(w0v.z, n0, fmaf(w0v.w, n1, bb0))));
        float pa1 = fmaf(w1v.x, o0, fmaf(w1v.y, o1, fmaf(w1v.z, n0, fmaf(w1v.w, n1, bb1))));
        float pb0 = fmaf(w0v.x, n0, fmaf(w0v.y, n1, fmaf(w0v.z, o0, fmaf(w0v.w, o1, bb0))));
        float pb1 = fmaf(w1v.x, n0, fmaf(w1v.y, n1, fmaf(w1v.z, o0, fmaf(w1v.w, o1, bb1))));
        float t0, t1, t2, t3;
        pade4(pa0, pa1, pb0, pb1, t0, t1, t2, t3);
        ba.h[p >> 1] = cvt_pkrtz(t0, t1);
        bb.h[p >> 1] = cvt_pkrtz(t2, t3);
    }

    f32x16 da, db;

    // --- layer 1: just-in-time fragment load (fenced), MFMA, quad-Pade ---
    asm volatile("" ::: "memory");
    {
        f16x8 aw;
        f32x16 c;
        #pragma unroll
        for (int p = 0; p < 8; ++p) {
            const int kk = SIG(g, p);
            aw[p] = (_Float16)sw[80 + wr + kk];
            c[p]  = sw[336 + kk];
        }
        #pragma unroll
        for (int p = 8; p < 16; ++p) c[p] = 0.0f;
        da = __builtin_amdgcn_mfma_f32_32x32x16_f16(aw, ba.v, c, 0, 0, 0);
        db = __builtin_amdgcn_mfma_f32_32x32x16_f16(aw, bb.v, c, 0, 0, 0);
    }
    #pragma unroll
    for (int p = 0; p < 8; p += 2) {
        float t0, t1, t2, t3;
        pade4(da[p], da[p + 1], db[p], db[p + 1], t0, t1, t2, t3);
        ba.h[p >> 1] = cvt_pkrtz(t0, t1);
        bb.h[p >> 1] = cvt_pkrtz(t2, t3);
    }

    // --- layer 2 ---
    asm volatile("" ::: "memory");
    {
        f16x8 aw;
        f32x16 c;
        #pragma unroll
        for (int p = 0; p < 8; ++p) {
            const int kk = SIG(g, p);
            aw[p] = (_Float16)sw[352 + wr + kk];
            c[p]  = sw[608 + kk];
        }
        #pragma unroll
        for (int p = 8; p < 16; ++p) c[p] = 0.0f;
        da = __builtin_amdgcn_mfma_f32_32x32x16_f16(aw, ba.v, c, 0, 0, 0);
        db = __builtin_amdgcn_mfma_f32_32x32x16_f16(aw, bb.v, c, 0, 0, 0);
    }
    #pragma unroll
    for (int p = 0; p < 8; p += 2) {
        float t0, t1, t2, t3;
        pade4(da[p], da[p + 1], db[p], db[p + 1], t0, t1, t2, t3);
        ba.h[p >> 1] = cvt_pkrtz(t0, t1);
        bb.h[p >> 1] = cvt_pkrtz(t2, t3);
    }

    // --- layer 3 ---
    asm volatile("" ::: "memory");
    {
        f16x8 aw;
        f32x16 c;
        #pragma unroll
        for (int p = 0; p < 8; ++p) {
            const int kk = SIG(g, p);
            aw[p] = (_Float16)sw[624 + wr + kk];
            c[p]  = sw[880 + kk];
        }
        #pragma unroll
        for (int p = 8; p < 16; ++p) c[p] = 0.0f;
        da = __builtin_amdgcn_mfma_f32_32x32x16_f16(aw, ba.v, c, 0, 0, 0);
        db = __builtin_amdgcn_mfma_f32_32x32x16_f16(aw, bb.v, c, 0, 0, 0);
    }

    // --- output head (16 -> 1): quad-Pade act, f32 dot; complement from
    //     lane^32. bout cancels in (pa - pb).
    asm volatile("" ::: "memory");
    float pa = 0.0f, pb = 0.0f;
    #pragma unroll
    for (int p = 0; p < 8; p += 2) {
        float t0, t1, t2, t3;
        pade4(da[p], da[p + 1], db[p], db[p + 1], t0, t1, t2, t3);
        const float w0 = sw[896 + SIG(g, p)];
        const float w1 = sw[896 + SIG(g, p + 1)];
        pa = fmaf(t0, w0, fmaf(t1, w1, pa));
        pb = fmaf(t2, w0, fmaf(t3, w1, pb));
    }
    pa += __shfl_xor(pa, 32);
    pb += __shfl_xor(pb, 32);

    const float tr  = fast_tanh(pa - pb);   // exact tanh for the final output
    const float fac = (tr < 0.0f) ? o0 : n0;
    if (lane < 32)
        ws[k * NVOX + vox] = tr * fac * g_dinv[k];
}

// ---------------------------------------------------------------------------
// Pass 2: per voxel u, total = sum_k ( f[k][u] - f[k][u - d_k] ).
__global__ __launch_bounds__(256)
void gather_kernel(const float* __restrict__ q,
                   const float* __restrict__ ws,
                   float* __restrict__ out)
{
    const int vox = blockIdx.x * 256 + threadIdx.x;

    const int z = vox % NSIDE;
    const int y = (vox / NSIDE) % NSIDE;
    const int x = vox / (NSIDE * NSIDE);
    const int xm = (x == 0) ? NSIDE - 1 : x - 1;
    const int ym = (y == 0) ? NSIDE - 1 : y - 1;
    const int yp = (y == NSIDE - 1) ? 0 : y + 1;
    const int zm = (z == 0) ? NSIDE - 1 : z - 1;
    const int zp = (z == NSIDE - 1) ? 0 : z + 1;

    float s = 0.0f;
    #pragma unroll
    for (int k = 0; k < NDIR; ++k) {
        const int px = g_ox[k] ? xm : x;
        const int py = (g_oy[k] > 0) ? ym : ((g_oy[k] < 0) ? yp : y);
        const int pz = (g_oz[k] > 0) ? zm : ((g_oz[k] < 0) ? zp : z);
        s += ws[k * NVOX + vox];
        s -= ws[k * NVOX + (px * NSIDE + py) * NSIDE + pz];
    }

    const float2 own = reinterpret_cast<const float2*>(q)[vox];
    float2 r;
    r.x = fmaf(s, SCALE, own.x);
    r.y = own.y;
    reinterpret_cast<float2*>(out)[vox] = r;
}

// ---------------------------------------------------------------------------
// Fallback: Round-3 single-pass scalar kernel (used only if ws is too small).
#define LAYER(WB, INA, INB, OUTA, OUTB)                                        \
    {                                                                          \
        _Pragma("unroll")                                                      \
        for (int i = 0; i < 16; ++i) {                                         \
            float aa = sw[(WB) + 256 + i];                                     \
            float ab = aa;                                                     \
            _Pragma("unroll")                                                  \
            for (int kk = 0; kk < 4; ++kk) {                                   \
                const float4 w = *reinterpret_cast<const float4*>(             \
                    &sw[(WB) + i * 16 + kk * 4]);                              \
                aa = fmaf(w.x, INA[4 * kk + 0], aa);                           \
                aa = fmaf(w.y, INA[4 * kk + 1], aa);                           \
                aa = fmaf(w.z, INA[4 * kk + 2], aa);                           \
                aa = fmaf(w.w, INA[4 * kk + 3], aa);                           \
                ab = fmaf(w.x, INB[4 * kk + 0], ab);                           \
                ab = fmaf(w.y, INB[4 * kk + 1], ab);                           \
                ab = fmaf(w.z, INB[4 * kk + 2], ab);                           \
                ab = fmaf(w.w, INB[4 * kk + 3], ab);                           \
            }                                                                  \
            OUTA[i] = fast_tanh(aa);                                           \
            OUTB[i] = fast_tanh(ab);                                           \
        }                                                                      \
    }

__global__ __launch_bounds__(256)
void automaton_kernel(const float* __restrict__ q,
                      const float* __restrict__ W0, const float* __restrict__ b0,
                      const float* __restrict__ W1, const float* __restrict__ b1,
                      const float* __restrict__ W2, const float* __restrict__ b2,
                      const float* __restrict__ W3, const float* __restrict__ b3,
                      const float* __restrict__ Wout, const float* __restrict__ bout,
                      float* __restrict__ out)
{
    STAGE_WEIGHTS_256()

    const int gid  = blockIdx.x * 256 + threadIdx.x;
    const int vox  = gid >> 1;
    const int half = gid & 1;

    const int z = vox % NSIDE;
    const int y = (vox / NSIDE) % NSIDE;
    const int x = vox / (NSIDE * NSIDE);
    const int xm = (x == 0) ? NSIDE - 1 : x - 1;
    const int xp = (x == NSIDE - 1) ? 0 : x + 1;
    const int ym = (y == 0) ? NSIDE - 1 : y - 1;
    const int yp = (y == NSIDE - 1) ? 0 : y + 1;
    const int zm = (z == 0) ? NSIDE - 1 : z - 1;
    const int zp = (z == NSIDE - 1) ? 0 : z + 1;

    const float2 own = reinterpret_cast<const float2*>(q)[vox];
    const float o0 = own.x, o1 = own.y;

    float sum = 0.0f;
    #pragma unroll 1
    for (int k = half * 13; k < half * 13 + 13; ++k) {
        asm volatile("" ::: "memory");   // block cross-iteration LICM of weight loads
        const int ox = c_ox[k], oy = c_oy[k], oz = c_oz[k];
        const int nx = (ox < 0) ? xm : ((ox > 0) ? xp : x);
        const int ny = (oy < 0) ? ym : ((oy > 0) ? yp : y);
        const int nz = (oz < 0) ? zm : ((oz > 0) ? zp : z);
        const float2 nbq = reinterpret_cast<const float2*>(q)[(nx * NSIDE + ny) * NSIDE + nz];
        const float n0 = nbq.x, n1 = nbq.y;

        float ha[16], hb[16], ta[16], tb[16];
        #pragma unroll
        for (int i = 0; i < 16; ++i) {
            const float4 w = *reinterpret_cast<const float4*>(&sw[i * 4]);
            const float bbias = sw[64 + i];
            float pa = fmaf(w.x, o0, fmaf(w.y, o1, fmaf(w.z, n0, fmaf(w.w, n1, bbias))));
            float pb = fmaf(w.x, n0, fmaf(w.y, n1, fmaf(w.z, o0, fmaf(w.w, o1, bbias))));
            ha[i] = fast_tanh(pa);
            hb[i] = fast_tanh(pb);
        }
        LAYER(80,  ha, hb, ta, tb)
        LAYER(352, ta, tb, ha, hb)
        LAYER(624, ha, hb, ta, tb)
        float oa = sw[912], ob = sw[912];
        #pragma unroll
        for (int kk = 0; kk < 4; ++kk) {
            const float4 w = *reinterpret_cast<const float4*>(&sw[896 + kk * 4]);
            oa = fmaf(w.x, ta[4 * kk + 0], oa);
            oa = fmaf(w.y, ta[4 * kk + 1], oa);
            oa = fmaf(w.z, ta[4 * kk + 2], oa);
            oa = fmaf(w.w, ta[4 * kk + 3], oa);
            ob = fmaf(w.x, tb[4 * kk + 0], ob);
            ob = fmaf(w.y, tb[4 * kk + 1], ob);
            ob = fmaf(w.z, tb[4 * kk + 2], ob);
            ob = fmaf(w.w, tb[4 * kk + 3], ob);
        }
        const float tr  = fast_tanh(oa - ob);
        const float fac = (tr < 0.0f) ? o0 : n0;
        sum = fmaf(tr * fac, c_dinv[k], sum);
    }

    sum += __shfl_xor(sum, 1);
    if (half == 0) {
        float2 r;
        r.x = fmaf(sum, SCALE, o0);
        r.y = o1;
        reinterpret_cast<float2*>(out)[vox] = r;
    }
}

extern "C" void kernel_launch(void* const* d_in, const int* in_sizes, int n_in,
                              void* d_out, int out_size, void* d_ws, size_t ws_size,
                              hipStream_t stream) {
    const float* q    = (const float*)d_in[0];
    const float* W0   = (const float*)d_in[1];
    const float* b0   = (const float*)d_in[2];
    const float* W1   = (const float*)d_in[3];
    const float* b1   = (const float*)d_in[4];
    const float* W2   = (const float*)d_in[5];
    const float* b2   = (const float*)d_in[6];
    const float* W3   = (const float*)d_in[7];
    const float* b3   = (const float*)d_in[8];
    const float* Wout = (const float*)d_in[9];
    const float* bout = (const float*)d_in[10];
    float* out = (float*)d_out;

    const size_t ws_needed = (size_t)NDIR * NVOX * sizeof(float);  // 5.75 MB
    if (ws_size >= ws_needed) {
        float* ws = (float*)d_ws;
        flux_mfma_kernel<<<dim3(NDIR * BLOCKS_PER_DIR), dim3(256), 0, stream>>>(
            q, W0, b0, W1, b1, W2, b2, W3, b3, Wout, bout, ws);
        gather_kernel<<<dim3(NVOX / 256), dim3(256), 0, stream>>>(q, ws, out);
    } else {
        automaton_kernel<<<dim3(NVOX * 2 / 256), dim3(256), 0, stream>>>(
            q, W0, b0, W1, b1, W2, b2, W3, b3, Wout, bout, out);
    }
}

// Round 14
// 57.012 us; speedup vs baseline: 1.3684x; 1.3684x over previous
//
#include <hip/hip_runtime.h>

static constexpr int NSIDE = 48;
static constexpr int NVOX  = NSIDE * NSIDE * NSIDE;   // 110592
static constexpr float SCALE = 0.041875863808787856f; // ONE_OVER_DIFF_TOT * DIFF_Q
static constexpr float ASCL = 2.8853900817779268f;    // 2*log2(e): tanh arg scale
static constexpr int NDIR  = 13;                      // canonical half of the 26 offsets
static constexpr int PAIRS_PER_BLOCK = 128;           // 4 waves x 32 pairs
static constexpr int BLOCKS_PER_DIR  = NVOX / PAIRS_PER_BLOCK;  // 864

typedef _Float16 f16x2 __attribute__((ext_vector_type(2)));
typedef _Float16 f16x8 __attribute__((ext_vector_type(8)));
typedef float    f32x16 __attribute__((ext_vector_type(16)));

union F16Frag { f16x2 h[4]; f16x8 v; };

// __builtin_amdgcn_cvt_pkrtz returns __fp16x2; bit-cast to our f16x2.
__device__ __forceinline__ f16x2 cvt_pkrtz(float a, float b) {
    return __builtin_bit_cast(f16x2, __builtin_amdgcn_cvt_pkrtz(a, b));
}

// Canonical directions (first nonzero component positive).
__device__ __constant__ int g_ox[NDIR] = { 1, 0, 0,  1, 1, 1, 1, 0, 0,  1, 1, 1, 1 };
__device__ __constant__ int g_oy[NDIR] = { 0, 1, 0,  1,-1, 0, 0, 1, 1,  1, 1,-1,-1 };
__device__ __constant__ int g_oz[NDIR] = { 0, 0, 1,  0, 0, 1,-1, 1,-1,  1,-1, 1,-1 };
__device__ __constant__ float g_dinv[NDIR] = {
    1.f, 1.f, 1.f,
    0.70710678118654752f, 0.70710678118654752f, 0.70710678118654752f,
    0.70710678118654752f, 0.70710678118654752f, 0.70710678118654752f,
    0.57735026918962576f, 0.57735026918962576f, 0.57735026918962576f, 0.57735026918962576f };

// Full 26-neighbor tables for the fallback single-pass kernel.
__device__ __constant__ int c_ox[26] = { 1,-1, 0, 0, 0, 0,
                                         1,-1, 1,-1, 1,-1, 1,-1, 0, 0, 0, 0,
                                         1, 1, 1, 1,-1,-1,-1,-1 };
__device__ __constant__ int c_oy[26] = { 0, 0, 1,-1, 0, 0,
                                         1, 1,-1,-1, 0, 0, 0, 0, 1,-1, 1,-1,
                                         1, 1,-1,-1, 1, 1,-1,-1 };
__device__ __constant__ int c_oz[26] = { 0, 0, 0, 0, 1,-1,
                                         0, 0, 0, 0, 1, 1,-1,-1, 1, 1,-1,-1,
                                         1,-1, 1,-1, 1,-1, 1,-1 };
__device__ __constant__ float c_dinv[26] = {
    1.f, 1.f, 1.f, 1.f, 1.f, 1.f,
    0.70710678118654752f, 0.70710678118654752f, 0.70710678118654752f, 0.70710678118654752f,
    0.70710678118654752f, 0.70710678118654752f, 0.70710678118654752f, 0.70710678118654752f,
    0.70710678118654752f, 0.70710678118654752f, 0.70710678118654752f, 0.70710678118654752f,
    0.57735026918962576f, 0.57735026918962576f, 0.57735026918962576f, 0.57735026918962576f,
    0.57735026918962576f, 0.57735026918962576f, 0.57735026918962576f, 0.57735026918962576f };

__device__ __forceinline__ float fast_tanh(float x) {
    // tanh(x) = 1 - 2/(exp2(2*log2e*x)+1); exact saturation at +-inf.
    float e = __builtin_amdgcn_exp2f(x * ASCL);
    float r = __builtin_amdgcn_rcpf(e + 1.0f);
    return fmaf(-2.0f, r, 1.0f);
}

// tanh for PRE-SCALED argument y = ASCL*x (scale folded into the weights):
// no v_mul -- 2 VALU + 2 trans. Keep exp2-based tanh: measured (R10/R13)
// trans~7cy vs VALU~4cy issue -- polynomial replacements always lose.
__device__ __forceinline__ float fast_tanh_pre(float y) {
    float e = __builtin_amdgcn_exp2f(y);
    float r = __builtin_amdgcn_rcpf(e + 1.0f);
    return fmaf(-2.0f, r, 1.0f);
}

// FLUX LDS layout (floats), W-rows PADDED to stride 20 (still 16B-aligned):
//  W0:[0,64) b0:[64,80)
//  W1:[80+r*20+c]  (r,c in 0..15) -> [80,396)   b1:[400,416)
//  W2:[416+r*20+c]                -> [416,732)  b2:[736,752)
//  W3:[752+r*20+c]                -> [752,1068) b3:[1072,1088)
//  Wout:[1088,1104) bout:[1104]
// Stride 16 put all rows in 2 bank-groups (8-way conflict on ds_read_b128,
// SQ_LDS_BANK_CONFLICT=3.2M since R5); stride 20 spreads rows over 8 offsets
// (~2-way = free per CDNA bank rules). All weights pre-scaled by ASCL.
#define STAGE_WEIGHTS_SCALED_PAD()                                             \
    __shared__ __align__(16) float sw[1108];                                   \
    {                                                                          \
        const int t_ = threadIdx.x;                                            \
        const int r_ = t_ >> 4, cc_ = t_ & 15;                                 \
        if (t_ <  64) sw[      t_] = W0[t_] * ASCL;                            \
        if (t_ <  16) sw[ 64 + t_] = b0[t_] * ASCL;                            \
                      sw[  80 + r_ * 20 + cc_] = W1[t_] * ASCL;                \
        if (t_ <  16) sw[ 400 + t_] = b1[t_] * ASCL;                           \
                      sw[ 416 + r_ * 20 + cc_] = W2[t_] * ASCL;                \
        if (t_ <  16) sw[ 736 + t_] = b2[t_] * ASCL;                           \
                      sw[ 752 + r_ * 20 + cc_] = W3[t_] * ASCL;                \
        if (t_ <  16) sw[1072 + t_] = b3[t_] * ASCL;                           \
        if (t_ <  16) sw[1088 + t_] = Wout[t_] * ASCL;                         \
        if (t_ ==  0) sw[1104]     = bout[0];                                  \
        __syncthreads();                                                       \
    }

// Unpadded layout for the fallback scalar kernel.
#define STAGE_WEIGHTS_256()                                                    \
    __shared__ __align__(16) float sw[916];                                    \
    {                                                                          \
        const int t_ = threadIdx.x;                                            \
        if (t_ <  64) sw[      t_] = W0[t_];                                   \
        if (t_ <  16) sw[ 64 + t_] = b0[t_];                                   \
                      sw[ 80 + t_] = W1[t_];                                   \
        if (t_ <  16) sw[336 + t_] = b1[t_];                                   \
                      sw[352 + t_] = W2[t_];                                   \
        if (t_ <  16) sw[608 + t_] = b2[t_];                                   \
                      sw[624 + t_] = W3[t_];                                   \
        if (t_ <  16) sw[880 + t_] = b3[t_];                                   \
        if (t_ <  16) sw[896 + t_] = Wout[t_];                                 \
        if (t_ ==  0) sw[912]     = bout[0];                                   \
    __syncthreads();                                                           \
    }

// sigma(g,p): k-index owned by lane-group g, fragment slot p. Same convention
// builds A (weights), C (biases) and B (inputs); D-chaining reproduces it, so
// any mismatch vs the HW's internal order cancels (verified on HW in R5).
#define SIG(G, P) (((P) < 4) ? 4 * (G) + (P) : 8 + 4 * (G) + ((P) - 4))

// ---------------------------------------------------------------------------
// MFMA flux kernel: R12 chassis verbatim (JIT fenced fragment loads, 40 VGPR,
// under the measured 64-VGPR occupancy cliff; exp2 tanh with ASCL folded
// into weights) + bank-conflict-free padded W layout.
__global__ __launch_bounds__(256)
void flux_mfma_kernel(const float* __restrict__ q,
                      const float* __restrict__ W0, const float* __restrict__ b0,
                      const float* __restrict__ W1, const float* __restrict__ b1,
                      const float* __restrict__ W2, const float* __restrict__ b2,
                      const float* __restrict__ W3, const float* __restrict__ b3,
                      const float* __restrict__ Wout, const float* __restrict__ bout,
                      float* __restrict__ ws)
{
    STAGE_WEIGHTS_SCALED_PAD()

    const int k    = blockIdx.x / BLOCKS_PER_DIR;                // 0..12
    const int rem  = blockIdx.x - k * BLOCKS_PER_DIR;
    const int lane = threadIdx.x & 63;
    const int wv   = threadIdx.x >> 6;
    const int g    = lane >> 5;                                  // feature-half 0/1
    const int vox  = rem * PAIRS_PER_BLOCK + wv * 32 + (lane & 31);

    const int z = vox % NSIDE;
    const int y = (vox / NSIDE) % NSIDE;
    const int x = vox / (NSIDE * NSIDE);
    const int ox = g_ox[k], oy = g_oy[k], oz = g_oz[k];
    const int nx = (ox > 0) ? ((x == NSIDE - 1) ? 0 : x + 1) : x;   // ox in {0,1}
    const int ny = (oy > 0) ? ((y == NSIDE - 1) ? 0 : y + 1)
                            : ((oy < 0) ? ((y == 0) ? NSIDE - 1 : y - 1) : y);
    const int nz = (oz > 0) ? ((z == NSIDE - 1) ? 0 : z + 1)
                            : ((oz < 0) ? ((z == 0) ? NSIDE - 1 : z - 1) : z);

    const float2 own = reinterpret_cast<const float2*>(q)[vox];
    const float2 nbq = reinterpret_cast<const float2*>(q)[(nx * NSIDE + ny) * NSIDE + nz];
    const float o0 = own.x, o1 = own.y;
    const float n0 = nbq.x, n1 = nbq.y;

    const int row  = lane & 31;       // A rows >=16 feed only D regs p>=8 (never read)
    const int wr20 = (row & 15) * 20; // padded W-row offset

    // --- layer 0 (4 -> 16): scaled dot4, mul-free tanh, pkrtz-packed ---
    F16Frag ba, bb;
    #pragma unroll
    for (int p = 0; p < 8; p += 2) {
        const int f0 = SIG(g, p), f1 = SIG(g, p + 1);
        const float4 w0v = *reinterpret_cast<const float4*>(&sw[f0 * 4]);
        const float4 w1v = *reinterpret_cast<const float4*>(&sw[f1 * 4]);
        const float bb0 = sw[64 + f0], bb1 = sw[64 + f1];
        float pa0 = fmaf(w0v.x, o0, fmaf(w0v.y, o1, fmaf(w0v.z, n0, fmaf(w0v.w, n1, bb0))));
        float pa1 = fmaf(w1v.x, o0, fmaf(w1v.y, o1, fmaf(w1v.z, n0, fmaf(w1v.w, n1, bb1))));
        float pb0 = fmaf(w0v.x, n0, fmaf(w0v.y, n1, fmaf(w0v.z, o0, fmaf(w0v.w, o1, bb0))));
        float pb1 = fmaf(w1v.x, n0, fmaf(w1v.y, n1, fmaf(w1v.z, o0, fmaf(w1v.w, o1, bb1))));
        ba.h[p >> 1] = cvt_pkrtz(fast_tanh_pre(pa0), fast_tanh_pre(pa1));
        bb.h[p >> 1] = cvt_pkrtz(fast_tanh_pre(pb0), fast_tanh_pre(pb1));
    }

    f32x16 da, db;

    // --- layer 1: just-in-time fragment load (fenced), MFMA, act ---
    asm volatile("" ::: "memory");   // fence: no hoisting of these LDS reads
    {
        f16x8 aw;
        f32x16 c;
        #pragma unroll
        for (int p = 0; p < 8; ++p) {
            const int kk = SIG(g, p);
            aw[p] = (_Float16)sw[80 + wr20 + kk];
            c[p]  = sw[400 + kk];
        }
        #pragma unroll
        for (int p = 8; p < 16; ++p) c[p] = 0.0f;
        da = __builtin_amdgcn_mfma_f32_32x32x16_f16(aw, ba.v, c, 0, 0, 0);
        db = __builtin_amdgcn_mfma_f32_32x32x16_f16(aw, bb.v, c, 0, 0, 0);
    }
    #pragma unroll
    for (int p = 0; p < 8; p += 2) {
        ba.h[p >> 1] = cvt_pkrtz(fast_tanh_pre(da[p]), fast_tanh_pre(da[p + 1]));
        bb.h[p >> 1] = cvt_pkrtz(fast_tanh_pre(db[p]), fast_tanh_pre(db[p + 1]));
    }

    // --- layer 2 ---
    asm volatile("" ::: "memory");
    {
        f16x8 aw;
        f32x16 c;
        #pragma unroll
        for (int p = 0; p < 8; ++p) {
            const int kk = SIG(g, p);
            aw[p] = (_Float16)sw[416 + wr20 + kk];
            c[p]  = sw[736 + kk];
        }
        #pragma unroll
        for (int p = 8; p < 16; ++p) c[p] = 0.0f;
        da = __builtin_amdgcn_mfma_f32_32x32x16_f16(aw, ba.v, c, 0, 0, 0);
        db = __builtin_amdgcn_mfma_f32_32x32x16_f16(aw, bb.v, c, 0, 0, 0);
    }
    #pragma unroll
    for (int p = 0; p < 8; p += 2) {
        ba.h[p >> 1] = cvt_pkrtz(fast_tanh_pre(da[p]), fast_tanh_pre(da[p + 1]));
        bb.h[p >> 1] = cvt_pkrtz(fast_tanh_pre(db[p]), fast_tanh_pre(db[p + 1]));
    }

    // --- layer 3 ---
    asm volatile("" ::: "memory");
    {
        f16x8 aw;
        f32x16 c;
        #pragma unroll
        for (int p = 0; p < 8; ++p) {
            const int kk = SIG(g, p);
            aw[p] = (_Float16)sw[752 + wr20 + kk];
            c[p]  = sw[1072 + kk];
        }
        #pragma unroll
        for (int p = 8; p < 16; ++p) c[p] = 0.0f;
        da = __builtin_amdgcn_mfma_f32_32x32x16_f16(aw, ba.v, c, 0, 0, 0);
        db = __builtin_amdgcn_mfma_f32_32x32x16_f16(aw, bb.v, c, 0, 0, 0);
    }

    // --- output head (16 -> 1): tanh then f32 partial dot with SCALED wout;
    //     pa-pb is the pre-scaled final argument. Complement from lane^32.
    asm volatile("" ::: "memory");
    float pa = 0.0f, pb = 0.0f;
    #pragma unroll
    for (int p = 0; p < 8; ++p) {
        const float wo = sw[1088 + SIG(g, p)];
        pa = fmaf(fast_tanh_pre(da[p]), wo, pa);
        pb = fmaf(fast_tanh_pre(db[p]), wo, pb);
    }
    pa += __shfl_xor(pa, 32);
    pb += __shfl_xor(pb, 32);

    const float tr  = fast_tanh_pre(pa - pb);   // arg pre-scaled via wout
    const float fac = (tr < 0.0f) ? o0 : n0;
    if (lane < 32)
        ws[k * NVOX + vox] = tr * fac * g_dinv[k];
}

// ---------------------------------------------------------------------------
// Pass 2: per voxel u, total = sum_k ( f[k][u] - f[k][u - d_k] ).
__global__ __launch_bounds__(256)
void gather_kernel(const float* __restrict__ q,
                   const float* __restrict__ ws,
                   float* __restrict__ out)
{
    const int vox = blockIdx.x * 256 + threadIdx.x;

    const int z = vox % NSIDE;
    const int y = (vox / NSIDE) % NSIDE;
    const int x = vox / (NSIDE * NSIDE);
    const int xm = (x == 0) ? NSIDE - 1 : x - 1;
    const int ym = (y == 0) ? NSIDE - 1 : y - 1;
    const int yp = (y == NSIDE - 1) ? 0 : y + 1;
    const int zm = (z == 0) ? NSIDE - 1 : z - 1;
    const int zp = (z == NSIDE - 1) ? 0 : z + 1;

    float s = 0.0f;
    #pragma unroll
    for (int k = 0; k < NDIR; ++k) {
        const int px = g_ox[k] ? xm : x;
        const int py = (g_oy[k] > 0) ? ym : ((g_oy[k] < 0) ? yp : y);
        const int pz = (g_oz[k] > 0) ? zm : ((g_oz[k] < 0) ? zp : z);
        s += ws[k * NVOX + vox];
        s -= ws[k * NVOX + (px * NSIDE + py) * NSIDE + pz];
    }

    const float2 own = reinterpret_cast<const float2*>(q)[vox];
    float2 r;
    r.x = fmaf(s, SCALE, own.x);
    r.y = own.y;
    reinterpret_cast<float2*>(out)[vox] = r;
}

// ---------------------------------------------------------------------------
// Fallback: Round-3 single-pass scalar kernel (used only if ws is too small).
#define LAYER(WB, INA, INB, OUTA, OUTB)                                        \
    {                                                                          \
        _Pragma("unroll")                                                      \
        for (int i = 0; i < 16; ++i) {                                         \
            float aa = sw[(WB) + 256 + i];                                     \
            float ab = aa;                                                     \
            _Pragma("unroll")                                                  \
            for (int kk = 0; kk < 4; ++kk) {                                   \
                const float4 w = *reinterpret_cast<const float4*>(             \
                    &sw[(WB) + i * 16 + kk * 4]);                              \
                aa = fmaf(w.x, INA[4 * kk + 0], aa);                           \
                aa = fmaf(w.y, INA[4 * kk + 1], aa);                           \
                aa = fmaf(w.z, INA[4 * kk + 2], aa);                           \
                aa = fmaf(w.w, INA[4 * kk + 3], aa);                           \
                ab = fmaf(w.x, INB[4 * kk + 0], ab);                           \
                ab = fmaf(w.y, INB[4 * kk + 1], ab);                           \
                ab = fmaf(w.z, INB[4 * kk + 2], ab);                           \
                ab = fmaf(w.w, INB[4 * kk + 3], ab);                           \
            }                                                                  \
            OUTA[i] = fast_tanh(aa);                                           \
            OUTB[i] = fast_tanh(ab);                                           \
        }                                                                      \
    }

__global__ __launch_bounds__(256)
void automaton_kernel(const float* __restrict__ q,
                      const float* __restrict__ W0, const float* __restrict__ b0,
                      const float* __restrict__ W1, const float* __restrict__ b1,
                      const float* __restrict__ W2, const float* __restrict__ b2,
                      const float* __restrict__ W3, const float* __restrict__ b3,
                      const float* __restrict__ Wout, const float* __restrict__ bout,
                      float* __restrict__ out)
{
    STAGE_WEIGHTS_256()

    const int gid  = blockIdx.x * 256 + threadIdx.x;
    const int vox  = gid >> 1;
    const int half = gid & 1;

    const int z = vox % NSIDE;
    const int y = (vox / NSIDE) % NSIDE;
    const int x = vox / (NSIDE * NSIDE);
    const int xm = (x == 0) ? NSIDE - 1 : x - 1;
    const int xp = (x == NSIDE - 1) ? 0 : x + 1;
    const int ym = (y == 0) ? NSIDE - 1 : y - 1;
    const int yp = (y == NSIDE - 1) ? 0 : y + 1;
    const int zm = (z == 0) ? NSIDE - 1 : z - 1;
    const int zp = (z == NSIDE - 1) ? 0 : z + 1;

    const float2 own = reinterpret_cast<const float2*>(q)[vox];
    const float o0 = own.x, o1 = own.y;

    float sum = 0.0f;
    #pragma unroll 1
    for (int k = half * 13; k < half * 13 + 13; ++k) {
        asm volatile("" ::: "memory");   // block cross-iteration LICM of weight loads
        const int ox = c_ox[k], oy = c_oy[k], oz = c_oz[k];
        const int nx = (ox < 0) ? xm : ((ox > 0) ? xp : x);
        const int ny = (oy < 0) ? ym : ((oy > 0) ? yp : y);
        const int nz = (oz < 0) ? zm : ((oz > 0) ? zp : z);
        const float2 nbq = reinterpret_cast<const float2*>(q)[(nx * NSIDE + ny) * NSIDE + nz];
        const float n0 = nbq.x, n1 = nbq.y;

        float ha[16], hb[16], ta[16], tb[16];
        #pragma unroll
        for (int i = 0; i < 16; ++i) {
            const float4 w = *reinterpret_cast<const float4*>(&sw[i * 4]);
            const float bbias = sw[64 + i];
            float pa = fmaf(w.x, o0, fmaf(w.y, o1, fmaf(w.z, n0, fmaf(w.w, n1, bbias))));
            float pb = fmaf(w.x, n0, fmaf(w.y, n1, fmaf(w.z, o0, fmaf(w.w, o1, bbias))));
            ha[i] = fast_tanh(pa);
            hb[i] = fast_tanh(pb);
        }
        LAYER(80,  ha, hb, ta, tb)
        LAYER(352, ta, tb, ha, hb)
        LAYER(624, ha, hb, ta, tb)
        float oa = sw[912], ob = sw[912];
        #pragma unroll
        for (int kk = 0; kk < 4; ++kk) {
            const float4 w = *reinterpret_cast<const float4*>(&sw[896 + kk * 4]);
            oa = fmaf(w.x, ta[4 * kk + 0], oa);
            oa = fmaf(w.y, ta[4 * kk + 1], oa);
            oa = fmaf(w.z, ta[4 * kk + 2], oa);
            oa = fmaf(w.w, ta[4 * kk + 3], oa);
            ob = fmaf(w.x, tb[4 * kk + 0], ob);
            ob = fmaf(w.y, tb[4 * kk + 1], ob);
            ob = fmaf(w.z, tb[4 * kk + 2], ob);
            ob = fmaf(w.w, tb[4 * kk + 3], ob);
        }
        const float tr  = fast_tanh(oa - ob);
        const float fac = (tr < 0.0f) ? o0 : n0;
        sum = fmaf(tr * fac, c_dinv[k], sum);
    }

    sum += __shfl_xor(sum, 1);
    if (half == 0) {
        float2 r;
        r.x = fmaf(sum, SCALE, o0);
        r.y = o1;
        reinterpret_cast<float2*>(out)[vox] = r;
    }
}

extern "C" void kernel_launch(void* const* d_in, const int* in_sizes, int n_in,
                              void* d_out, int out_size, void* d_ws, size_t ws_size,
                              hipStream_t stream) {
    const float* q    = (const float*)d_in[0];
    const float* W0   = (const float*)d_in[1];
    const float* b0   = (const float*)d_in[2];
    const float* W1   = (const float*)d_in[3];
    const float* b1   = (const float*)d_in[4];
    const float* W2   = (const float*)d_in[5];
    const float* b2   = (const float*)d_in[6];
    const float* W3   = (const float*)d_in[7];
    const float* b3   = (const float*)d_in[8];
    const float* Wout = (const float*)d_in[9];
    const float* bout = (const float*)d_in[10];
    float* out = (float*)d_out;

    const size_t ws_needed = (size_t)NDIR * NVOX * sizeof(float);  // 5.75 MB
    if (ws_size >= ws_needed) {
        float* ws = (float*)d_ws;
        flux_mfma_kernel<<<dim3(NDIR * BLOCKS_PER_DIR), dim3(256), 0, stream>>>(
            q, W0, b0, W1, b1, W2, b2, W3, b3, Wout, bout, ws);
        gather_kernel<<<dim3(NVOX / 256), dim3(256), 0, stream>>>(q, ws, out);
    } else {
        automaton_kernel<<<dim3(NVOX * 2 / 256), dim3(256), 0, stream>>>(
            q, W0, b0, W1, b1, W2, b2, W3, b3, Wout, bout, out);
    }
}